// Round 4
// baseline (330.503 us; speedup 1.0000x reference)
//
#include <hip/hip_runtime.h>
#include <hip/hip_fp16.h>

#define HH 512
#define WW 512
#define NCH 3
#define NBATCH 16
#define NIMG (NBATCH*NCH)     // 48
#define CHUNK 32              // output rows per wave
#define NCHUNK (HH/CHUNK)     // 16
#define NSTRIP 4              // 128-col strips
#define SW 128
#define SLOTS 140             // cols c0-5 .. c0+132 at slot = col-c0+5
#define NT 64                 // one wave per block -> no barriers anywhere
#define NROWS (CHUNK+10)      // 42 input rows per wave
#define BLKS_PER_B (NCH*NCHUNK*NSTRIP)   // 192 partial slots per batch elem
#define NRLDS 4               // ring slots 7..10 live in LDS; 0..6 in registers

template<int N> struct SlotTag { static constexpr int v = N; };

struct RowData { float4 m; float2 h; };
struct RingR { __half2 a, b, c, d; };    // struct of scalars: SROA-trivial

__device__ __forceinline__ float4 packR(const RingR& q) {
  return make_float4(__builtin_bit_cast(float, q.a), __builtin_bit_cast(float, q.b),
                     __builtin_bit_cast(float, q.c), __builtin_bit_cast(float, q.d));
}
__device__ __forceinline__ RingR unpackR(float4 f) {
  RingR q;
  q.a = __builtin_bit_cast(__half2, f.x); q.b = __builtin_bit_cast(__half2, f.y);
  q.c = __builtin_bit_cast(__half2, f.z); q.d = __builtin_bit_cast(__half2, f.w);
  return q;
}

// R11: occupancy was the real cap. OccupancyPercent ~16% = 5 blocks/CU matches
// a ~64KB effective LDS pool / 12.8KB block (R9's 2.5KB-LDS variant showed 34%,
// grid-limited — confirming LDS is the binding resource despite the 160KB spec).
// Fix: 7 of 11 ring slots -> named register structs (compile-time slot via
// SlotTag + if constexpr chains; NO arrays/unions -> cannot repeat R9's
// scratch disaster). 4 slots stay in LDS. LDS 13824 -> ~6656B: 5 -> 9+ blocks
// /CU. Arithmetic bit-identical to R7/R10 (absmax 0.0).
__global__ __launch_bounds__(NT) void ssim_main(
    const float* __restrict__ pred, const float* __restrict__ targ,
    float* __restrict__ ws)
{
  // row staging, 2 buffers: slot s holds (x,y) of col c0+s-5 (same-wave LDS
  // is in-order; no barriers needed — validated R2-R10, absmax 0.0)
  __shared__ __align__(16) float2 rowb[2][SLOTS];
  // LDS part of the fp16 ring (slots 7..10): one 16B word per (slot,lane),
  // b128 access = conflict-free 16B/lane pattern
  __shared__ __align__(16) float4 ringl[NRLDS][NT];

  const int l = threadIdx.x;
  const int blk = blockIdx.x;
  const int img = blk >> 6;              // / (NCHUNK*NSTRIP)
  const int rem = blk & 63;
  const int chunk = rem >> 2;
  const int strip = rem & 3;

  const int r0 = chunk*CHUNK - 5;        // first input row
  const int c0 = strip*SW;

  // zero the pad slots once in BOTH buffers (image-edge strips keep them zero)
  if (l < 10) {
    const int s = (l < 5) ? l : (128 + l);
    rowb[0][s] = make_float2(0.f, 0.f);
    rowb[1][s] = make_float2(0.f, 0.f);
  }

  const size_t ib = (size_t)img * (size_t)(HH*WW);
  const float* pp = pred + ib;
  const float* tp = targ + ib;

  const int cm = c0 + 2*l;               // this lane's 2 main cols
  const int h  = l - 54;                 // halo id 0..9 on lanes 54..63
  const int ch = (h < 5) ? (c0 - 5 + h) : (c0 + 123 + h);   // halo col
  const bool hval = (l >= 54) && ((unsigned)ch < (unsigned)WW);
  const int hs = (h < 5) ? h : (128 + h);                    // halo slot

  auto loadrow = [&](int it) -> RowData {
    RowData d;
    const int r = r0 + it;
    if ((unsigned)r < (unsigned)HH) {    // wave-uniform branch
      const size_t ro = (size_t)r * WW;
      const float2 x = *(const float2*)(pp + ro + cm);
      const float2 y = *(const float2*)(tp + ro + cm);
      d.m = make_float4(x.x, x.y, y.x, y.y);
      if (hval) d.h = make_float2(pp[ro + ch], tp[ro + ch]);
      else      d.h = make_float2(0.f, 0.f);
    } else {
      d.m = make_float4(0.f, 0.f, 0.f, 0.f);
      d.h = make_float2(0.f, 0.f);
    }
    return d;
  };

  auto stage = [&](int b, const RowData& d) {
    // interleaved (x,y) so taps read as aligned float4
    rowb[b][5 + 2*l] = make_float2(d.m.x, d.m.z);
    rowb[b][6 + 2*l] = make_float2(d.m.y, d.m.w);
    if (hval) rowb[b][hs] = d.h;
  };

  // register ring slots 0..6 (named scalars -> guaranteed registers)
  RingR r0s, r1s, r2s, r3s, r4s, r5s, r6s;

  // vertical running sums: (x, y, xy, ss=xx+yy) per col — registers
  float2 vx = make_float2(0.f,0.f), vy = vx, vxy = vx, vss = vx;
  float acc = 0.f;

  // prologue: stage row 0 into buf 0, then 3-deep global prefetch (rows 1..3)
  {
    RowData row0d = loadrow(0);
    stage(0, row0d);
  }
  RowData cur = loadrow(1);
  RowData nxt = loadrow(2);
  RowData nx2 = loadrow(3);

  constexpr float c1 = 0.0001f, c2 = 0.0009f, inv121 = 1.0f/121.0f;

  auto ssim1 = [&](float Sx, float Sy, float Sxy, float Sss) -> float {
    const float mux = Sx*inv121, muy = Sy*inv121;
    const float muxy = mux*muy;
    const float m2   = fmaf(mux, mux, muy*muy);
    const float sgxy = fmaf(Sxy, inv121, -muxy);
    const float sgss = fmaf(Sss, inv121, -m2);
    const float num = fmaf(2.f, muxy, c1) * fmaf(2.f, sgxy, c2);
    const float den = (m2 + c1) * (sgss + c2);
    const float s = num * __builtin_amdgcn_rcpf(den);
    return fminf(fmaxf(s, 0.f), 1.f);
  };

  auto body = [&](auto SC, int it, bool dosub, bool doemit) {
    constexpr int slot = decltype(SC)::v;
    const int b = it & 1;

    // tap reads FIRST, from the buffer staged LAST iteration
    // taps p=0..11 <-> local cols 2l-5 .. 2l+6 <-> slots 2l .. 2l+11
    const float4* tb = (const float4*)(rowb[b] + 2*l);
    float4 tv[6];
    #pragma unroll
    for (int j = 0; j < 6; ++j) tv[j] = tb[j];

    // stage NEXT row into the other buffer
    stage(b ^ 1, cur);
    cur = nxt; nxt = nx2;
    nx2 = loadrow(it + 4);               // global prefetch 3 rows ahead

    // ring-old: registers for slots 0..6, LDS b128 for 7..10
    RingR ou;
    if (dosub) {
      if constexpr (slot >= 7)      ou = unpackR(ringl[slot - 7][l]);
      else if constexpr (slot == 0) ou = r0s;
      else if constexpr (slot == 1) ou = r1s;
      else if constexpr (slot == 2) ou = r2s;
      else if constexpr (slot == 3) ou = r3s;
      else if constexpr (slot == 4) ou = r4s;
      else if constexpr (slot == 5) ou = r5s;
      else                          ou = r6s;
    }

    float sx=0.f, sy=0.f, sxy=0.f, sss=0.f;
    float x0=0.f, y0=0.f, x11=0.f, y11=0.f;
    #pragma unroll
    for (int j = 0; j < 6; ++j) {
      const float4 v = tv[j];            // (x[p], y[p], x[p+1], y[p+1]), p=2j
      if (j == 0) { x0 = v.x; y0 = v.y; }
      sx += v.x; sy += v.y;
      sxy = fmaf(v.x, v.y, sxy);
      sss = fmaf(v.x, v.x, sss);
      sss = fmaf(v.y, v.y, sss);
      if (j < 5) {
        sx += v.z; sy += v.w;
        sxy = fmaf(v.z, v.w, sxy);
        sss = fmaf(v.z, v.z, sss);
        sss = fmaf(v.w, v.w, sss);
      } else { x11 = v.z; y11 = v.w; }
    }

    // col0 window = p0..p10 ; col1 = col0 - p0 + p11
    const float2 hx  = make_float2(sx,  sx - x0 + x11);
    const float2 hy  = make_float2(sy,  sy - y0 + y11);
    const float2 hxy = make_float2(sxy, fmaf(x11, y11, fmaf(-x0, y0, sxy)));
    const float2 hss = make_float2(sss,
        fmaf(x11, x11, fmaf(y11, y11, fmaf(-x0, x0, fmaf(-y0, y0, sss)))));

    // round h to fp16 once; add the rounded value and store the identical
    // rounded value -> later subtract cancels exactly (no drift)
    RingR qu;
    qu.a = __floats2half2_rn(hx.x,  hy.x);
    qu.b = __floats2half2_rn(hxy.x, hss.x);
    qu.c = __floats2half2_rn(hx.y,  hy.y);
    qu.d = __floats2half2_rn(hxy.y, hss.y);
    if constexpr (slot >= 7)      ringl[slot - 7][l] = packR(qu);
    else if constexpr (slot == 0) r0s = qu;
    else if constexpr (slot == 1) r1s = qu;
    else if constexpr (slot == 2) r2s = qu;
    else if constexpr (slot == 3) r3s = qu;
    else if constexpr (slot == 4) r4s = qu;
    else if constexpr (slot == 5) r5s = qu;
    else                          r6s = qu;

    const float2 a0 = __half22float2(qu.a), a1 = __half22float2(qu.b);
    const float2 a2 = __half22float2(qu.c), a3 = __half22float2(qu.d);

    if (dosub) {
      const float2 o0 = __half22float2(ou.a), o1 = __half22float2(ou.b);
      const float2 o2 = __half22float2(ou.c), o3 = __half22float2(ou.d);
      vx.x  -= o0.x; vy.x  -= o0.y; vxy.x -= o1.x; vss.x -= o1.y;
      vx.y  -= o2.x; vy.y  -= o2.y; vxy.y -= o3.x; vss.y -= o3.y;
    }
    vx.x += a0.x; vy.x += a0.y; vxy.x += a1.x; vss.x += a1.y;
    vx.y += a2.x; vy.y += a2.y; vxy.y += a3.x; vss.y += a3.y;

    if (doemit) {
      acc += ssim1(vx.x, vy.x, vxy.x, vss.x);
      acc += ssim1(vx.y, vy.y, vxy.y, vss.y);
    }
  };

  // 42 input rows: warmup 11 (first emit at it=10), steady 2x11, tail 9
  #define B_(U,IT,DS,DE) body(SlotTag<U>{}, IT, DS, DE);
  B_(0,0,false,false)  B_(1,1,false,false)  B_(2,2,false,false)
  B_(3,3,false,false)  B_(4,4,false,false)  B_(5,5,false,false)
  B_(6,6,false,false)  B_(7,7,false,false)  B_(8,8,false,false)
  B_(9,9,false,false)  B_(10,10,false,true)

  B_(0,11,true,true)  B_(1,12,true,true)  B_(2,13,true,true)
  B_(3,14,true,true)  B_(4,15,true,true)  B_(5,16,true,true)
  B_(6,17,true,true)  B_(7,18,true,true)  B_(8,19,true,true)
  B_(9,20,true,true)  B_(10,21,true,true)

  B_(0,22,true,true)  B_(1,23,true,true)  B_(2,24,true,true)
  B_(3,25,true,true)  B_(4,26,true,true)  B_(5,27,true,true)
  B_(6,28,true,true)  B_(7,29,true,true)  B_(8,30,true,true)
  B_(9,31,true,true)  B_(10,32,true,true)

  B_(0,33,true,true)  B_(1,34,true,true)  B_(2,35,true,true)
  B_(3,36,true,true)  B_(4,37,true,true)  B_(5,38,true,true)
  B_(6,39,true,true)  B_(7,40,true,true)  B_(8,41,true,true)
  #undef B_

  // wave reduction -> per-block partial slot (written unconditionally: no
  // memset of d_ws needed, no atomics)
  #pragma unroll
  for (int off = 32; off > 0; off >>= 1) acc += __shfl_down(acc, off, 64);
  if (l == 0) ws[blk] = acc;
}

__global__ void ssim_final(const float* __restrict__ ws, float* __restrict__ out) {
  const int b = blockIdx.x;              // batch element
  const int t = threadIdx.x;             // 64 threads
  const float* p = ws + b * BLKS_PER_B;
  float s = p[t] + p[t + 64] + p[t + 128];
  #pragma unroll
  for (int off = 32; off > 0; off >>= 1) s += __shfl_down(s, off, 64);
  if (t == 0) out[b] = 1.0f - s * (1.0f / (float)(NCH*HH*WW));
}

extern "C" void kernel_launch(void* const* d_in, const int* in_sizes, int n_in,
                              void* d_out, int out_size, void* d_ws, size_t ws_size,
                              hipStream_t stream) {
  const float* pred = (const float*)d_in[0];
  const float* targ = (const float*)d_in[1];
  float* out = (float*)d_out;
  float* ws  = (float*)d_ws;
  ssim_main<<<dim3(NIMG*NCHUNK*NSTRIP), dim3(NT), 0, stream>>>(pred, targ, ws);
  ssim_final<<<dim3(NBATCH), dim3(64), 0, stream>>>(ws, out);
}